// Round 3
// baseline (248.285 us; speedup 1.0000x reference)
//
#include <hip/hip_runtime.h>

// (B,N,D,K) = (32, 2048, 512, 256)
#define CB 32
#define CN 2048
#define CD 512
#define CK 256

typedef __bf16 bf16x8 __attribute__((ext_vector_type(8)));
typedef float  f32x4  __attribute__((ext_vector_type(4)));

__device__ __forceinline__ unsigned pk2bf(float a, float b) {   // RNE pack: 2 f32 -> bf16x2
    union { float f; unsigned u; } x, y; x.f = a; y.f = b;
    unsigned ru = x.u + 0x7fffu + ((x.u >> 16) & 1u);
    unsigned rv = y.u + 0x7fffu + ((y.u >> 16) & 1u);
    return (ru >> 16) | (rv & 0xffff0000u);
}

__device__ __forceinline__ unsigned short bf16r(float a) {      // RNE f32 -> bf16
    union { float f; unsigned u; } x; x.f = a;
    unsigned r = x.u + 0x7fffu + ((x.u >> 16) & 1u);
    return (unsigned short)(r >> 16);
}

__device__ __forceinline__ void glds16(const void* g, void* l) {
    __builtin_amdgcn_global_load_lds(
        (const __attribute__((address_space(1))) void*)g,
        (__attribute__((address_space(3))) void*)l, 16, 0, 0);
}

// ---------------- K0: prep = {WiT transpose tiles: blocks 0..31} ∪
//                          {vQp partial GEMV: blocks 32..287} ----------------
__global__ __launch_bounds__(256) void prep_kernel(
        const float* __restrict__ Wi, const float* __restrict__ Wq,
        const float* __restrict__ vQ, const float* __restrict__ bq,
        unsigned short* __restrict__ WiT, float* __restrict__ vQpP)
{
    const int tid = threadIdx.x;
    if (blockIdx.x < 32) {
        // 64x64 tile transpose Wi[d][k] -> WiT[k][d] (bf16), coalesced both sides
        const int t = blockIdx.x;
        const int d0 = (t >> 2) * 64, k0 = (t & 3) * 64;
        __shared__ float sT[64][68];                 // pad 68: 16B-aligned rows
        const int r = tid >> 4, c4 = (tid & 15) * 4;
        #pragma unroll
        for (int i = 0; i < 4; ++i) {
            float4 v = *reinterpret_cast<const float4*>(
                Wi + (size_t)(d0 + r + i * 16) * CK + k0 + c4);
            *reinterpret_cast<float4*>(&sT[r + i * 16][c4]) = v;
        }
        __syncthreads();
        const int k = tid >> 2, dg = (tid & 3) * 16;
        unsigned short __attribute__((aligned(16))) ov[16];
        #pragma unroll
        for (int j = 0; j < 16; ++j) ov[j] = bf16r(sT[dg + j][k]);
        unsigned short* dst = WiT + (size_t)(k0 + k) * CD + d0 + dg;
        *reinterpret_cast<uint4*>(dst)     = *reinterpret_cast<const uint4*>(&ov[0]);
        *reinterpret_cast<uint4*>(dst + 8) = *reinterpret_cast<const uint4*>(&ov[8]);
    } else {
        // vQpP[b][j][k] = sum_{d in 64-slice j} vQ[b][d]*Wq[d][k]  (+bq at j==0)
        const int bb = blockIdx.x - 32;
        const int b = bb >> 3, j = bb & 7;
        __shared__ float sq[64];
        if (tid < 64) sq[tid] = vQ[b * CD + j * 64 + tid];
        __syncthreads();
        float acc = (j == 0) ? bq[tid] : 0.f;
        const float* wq = Wq + (size_t)j * 64 * CK + tid;
        #pragma unroll
        for (int d = 0; d < 64; d += 8) {
            float wv[8];
            #pragma unroll
            for (int u = 0; u < 8; ++u) wv[u] = wq[(d + u) * CK];   // 8 loads in flight
            #pragma unroll
            for (int u = 0; u < 8; ++u) acc += sq[d + u] * wv[u];
        }
        vQpP[(size_t)bb * CK + tid] = acc;
    }
}

// ---------------- K1: fused scores + online-softmax + K-space num ----------------
// BM=128 rows/block, all K=256 cols, BK=64. grid (16, 32).
// A (vI) loaded DIRECTLY global->reg (no LDS stage, no per-step A barrier);
// B (WiT) double-buffered in LDS with glds prefetch issued before compute
// (T3-minimum schedule: one barrier per K-step, stage(t+1) || compute(t)).
__global__ __launch_bounds__(256, 2) void scores_fused_kernel(
        const float* __restrict__ vI, const unsigned short* __restrict__ WiT,
        const float* __restrict__ vQpP, const float* __restrict__ Wp,
        float* __restrict__ numP, float* __restrict__ Zp, float* __restrict__ mP)
{
    constexpr int BM = 128, BK = 64;
    __shared__ __align__(16) unsigned short sB[2][CK * BK];    // 2 x 32 KB
    float* sred = (float*)sB[0];          // [4][128]   (aliased after K-loop)
    float* sS   = ((float*)sB[0]) + 512;  // [128]
    float* sW   = ((float*)sB[0]) + 640;  // [128]

    const int tid  = threadIdx.x;
    const int b    = blockIdx.y;
    const int n0   = blockIdx.x * BM;
    const int wave = tid >> 6;
    const int lane = tid & 63;
    const int col  = lane & 15;
    const int quad = lane >> 4;

    const float* vIb   = vI + ((size_t)b * CN + n0) * CD;
    const float* aBase = vIb + (size_t)col * CD + quad * 8;   // + mt*16*CD + d0 + s*32

    // B glds source offsets (swizzled chunk): instr t covers rows wave*64+t*8 .. +8
    int gBoff[8];
    #pragma unroll
    for (int t = 0; t < 8; ++t) {
        int row = wave * 64 + t * 8 + (lane >> 3);
        int c   = (lane & 7) ^ (row & 7);
        gBoff[t] = row * CD + c * 8;    // ushort index; +d0 per chunk
    }

    f32x4 acc[8][4];
    #pragma unroll
    for (int mt = 0; mt < 8; ++mt)
        #pragma unroll
        for (int kt = 0; kt < 4; ++kt)
            acc[mt][kt] = (f32x4){0.f, 0.f, 0.f, 0.f};

    // prologue: stage B(0) into buf0
    #pragma unroll
    for (int i = 0; i < 8; ++i)
        glds16(WiT + gBoff[i], (unsigned short*)sB[0] + (wave * 8 + i) * 512);
    __syncthreads();

    for (int t = 0; t < 8; ++t) {
        const int d0 = t * BK;
        const unsigned short* bufC = sB[t & 1];

        // ---- s = 0: issue A loads first (oldest in vmcnt queue) ----
        f32x4 a0[8], a1[8];
        #pragma unroll
        for (int mt = 0; mt < 8; ++mt) {
            const float* p = aBase + (size_t)(mt * 16) * CD + d0;
            a0[mt] = *reinterpret_cast<const f32x4*>(p);
            a1[mt] = *reinterpret_cast<const f32x4*>(p + 4);
        }
        // ---- prefetch B(t+1) into the other buffer (completes by barrier) ----
        if (t < 7) {
            #pragma unroll
            for (int i = 0; i < 8; ++i)
                glds16(WiT + gBoff[i] + d0 + BK,
                       (unsigned short*)sB[(t + 1) & 1] + (wave * 8 + i) * 512);
        }
        #pragma unroll
        for (int s = 0; s < 2; ++s) {
            if (s == 1) {   // reuse a0/a1 registers for the second K-slice
                #pragma unroll
                for (int mt = 0; mt < 8; ++mt) {
                    const float* p = aBase + (size_t)(mt * 16) * CD + d0 + 32;
                    a0[mt] = *reinterpret_cast<const f32x4*>(p);
                    a1[mt] = *reinterpret_cast<const f32x4*>(p + 4);
                }
            }
            const int slot = (4 * s + quad) ^ (col & 7);
            bf16x8 bfr[4];
            #pragma unroll
            for (int kt = 0; kt < 4; ++kt) {
                int R = wave * 64 + kt * 16 + col;
                bfr[kt] = *reinterpret_cast<const bf16x8*>(bufC + R * 64 + slot * 8);
            }
            #pragma unroll
            for (int mt = 0; mt < 8; ++mt) {
                union { unsigned u[4]; bf16x8 v; } af;
                af.u[0] = pk2bf(a0[mt].x, a0[mt].y);
                af.u[1] = pk2bf(a0[mt].z, a0[mt].w);
                af.u[2] = pk2bf(a1[mt].x, a1[mt].y);
                af.u[3] = pk2bf(a1[mt].z, a1[mt].w);
                #pragma unroll
                for (int kt = 0; kt < 4; ++kt)
                    acc[mt][kt] = __builtin_amdgcn_mfma_f32_16x16x32_bf16(
                        af.v, bfr[kt], acc[mt][kt], 0, 0, 0);
            }
        }
        __syncthreads();   // drains vmcnt: B(t+1) staged; buf swap safe
    }

    // ---- epilogue 1: per-row scores (vIp never materialized) ----
    float vq[4], wp[4];
    #pragma unroll
    for (int kt = 0; kt < 4; ++kt) {
        int k = wave * 64 + kt * 16 + col;
        float a = 0.f;
        #pragma unroll
        for (int j = 0; j < 8; ++j) a += vQpP[(b * 8 + j) * CK + k];  // combine partials
        vq[kt] = a;
        wp[kt] = Wp[k];
    }
    float sp[8][4];
    #pragma unroll
    for (int mt = 0; mt < 8; ++mt)
        #pragma unroll
        for (int r = 0; r < 4; ++r) {
            float s = 0.f;
            #pragma unroll
            for (int kt = 0; kt < 4; ++kt) {
                float v = acc[mt][kt][r] + vq[kt];
                v = v > 0.f ? v : 0.01f * v;
                s += v * wp[kt];
            }
            sp[mt][r] = s;
        }
    #pragma unroll
    for (int off = 1; off < 16; off <<= 1)
        #pragma unroll
        for (int mt = 0; mt < 8; ++mt)
            #pragma unroll
            for (int r = 0; r < 4; ++r)
                sp[mt][r] += __shfl_xor(sp[mt][r], off);

    __syncthreads();   // all sB ds_reads done; safe to alias
    if (col == 0) {
        #pragma unroll
        for (int mt = 0; mt < 8; ++mt)
            #pragma unroll
            for (int r = 0; r < 4; ++r)
                sred[wave * 128 + mt * 16 + quad * 4 + r] = sp[mt][r];
    }
    __syncthreads();
    if (tid < BM)
        sS[tid] = sred[tid] + sred[128 + tid] + sred[256 + tid] + sred[384 + tid];
    __syncthreads();

    // ---- epilogue 2: block-local softmax pieces ----
    float m = -1e30f;
    #pragma unroll 8
    for (int i = 0; i < BM; ++i) m = fmaxf(m, sS[i]);
    if (tid < BM) sW[tid] = __expf(sS[tid] - m);
    __syncthreads();
    float z = (tid < BM) ? sW[tid] : 0.f;
    #pragma unroll
    for (int off = 32; off > 0; off >>= 1) z += __shfl_xor(z, off);
    if (lane == 0) sS[wave] = z;     // sS scores no longer needed
    __syncthreads();
    const int pidx = b * 16 + blockIdx.x;
    if (tid == 0) {
        Zp[pidx] = sS[0] + sS[1] + sS[2] + sS[3];
        mP[pidx] = m;
    }

    // ---- epilogue 3: K-space num from acc registers, no vI re-read ----
    // lane owns rows {mt*16+quad*4+r}, cols k = wave*64+kt*16+col
    float nk[4] = {0.f, 0.f, 0.f, 0.f};
    #pragma unroll
    for (int mt = 0; mt < 8; ++mt)
        #pragma unroll
        for (int r = 0; r < 4; ++r) {
            float w = sW[mt * 16 + quad * 4 + r];    // LDS broadcast within quad
            #pragma unroll
            for (int kt = 0; kt < 4; ++kt)
                nk[kt] += w * acc[mt][kt][r];
        }
    #pragma unroll
    for (int kt = 0; kt < 4; ++kt) {                 // reduce the 4 quads
        nk[kt] += __shfl_xor(nk[kt], 16);
        nk[kt] += __shfl_xor(nk[kt], 32);
    }
    if (quad == 0) {
        #pragma unroll
        for (int kt = 0; kt < 4; ++kt)
            numP[(size_t)pidx * CK + wave * 64 + kt * 16 + col] = nk[kt];
    }
}

// ---------------- K2: combine partials -> out = num/Z + vQp (elementwise) ----------------
__global__ __launch_bounds__(256) void finalize_kernel(
        const float* __restrict__ numP, const float* __restrict__ Zp,
        const float* __restrict__ mP, const float* __restrict__ vQpP,
        float* __restrict__ out)
{
    const int b = blockIdx.x, tid = threadIdx.x;
    float M = -1e30f;
    #pragma unroll
    for (int j = 0; j < 16; ++j) M = fmaxf(M, mP[b * 16 + j]);
    float w[16]; float Zt = 0.f;
    #pragma unroll
    for (int j = 0; j < 16; ++j) {
        w[j] = __expf(mP[b * 16 + j] - M);
        Zt += w[j] * Zp[b * 16 + j];
    }
    const float inv = 1.f / Zt;
    float s = 0.f;
    #pragma unroll
    for (int j = 0; j < 16; ++j) s += w[j] * numP[(size_t)(b * 16 + j) * CK + tid];
    float vq = 0.f;
    #pragma unroll
    for (int j = 0; j < 8; ++j) vq += vQpP[(size_t)(b * 8 + j) * CK + tid];
    out[b * CK + tid] = s * inv + vq;
}

extern "C" void kernel_launch(void* const* d_in, const int* in_sizes, int n_in,
                              void* d_out, int out_size, void* d_ws, size_t ws_size,
                              hipStream_t stream)
{
    const float* vI = (const float*)d_in[0];   // [B,N,D]
    const float* vQ = (const float*)d_in[1];   // [B,D]
    const float* Wi = (const float*)d_in[2];   // [D,K]
    const float* Wq = (const float*)d_in[3];   // [D,K]
    const float* bq = (const float*)d_in[4];   // [K]
    const float* Wp = (const float*)d_in[5];   // [K,1]
    // d_in[6] = bp: softmax-invariant, unused
    float* out = (float*)d_out;                // [B,K]

    char* ws = (char*)d_ws;
    float*          vQpP = (float*)(ws);                   // 256 KB  [32*8][256]
    unsigned short* WiT  = (unsigned short*)(ws + 262144); // 256 KB  [256][512]
    float*          numP = (float*)(ws + 524288);          // 512 KB  [32*16][256]
    float*          Zp   = (float*)(ws + 524288 + 524288); //   2 KB
    float*          mP   = (float*)(ws + 1048576 + 2048);  //   2 KB

    prep_kernel        <<<288, 256, 0, stream>>>(Wi, Wq, vQ, bq, WiT, vQpP);
    scores_fused_kernel<<<dim3(CN / 128, CB), 256, 0, stream>>>(vI, WiT, vQpP, Wp,
                                                                numP, Zp, mP);
    finalize_kernel    <<<CB, 256, 0, stream>>>(numP, Zp, mP, vQpP, out);
}

// Round 4
// 223.570 us; speedup vs baseline: 1.1105x; 1.1105x over previous
//
#include <hip/hip_runtime.h>

// (B,N,D,K) = (32, 2048, 512, 256)
#define CB 32
#define CN 2048
#define CD 512
#define CK 256

typedef __bf16 bf16x8 __attribute__((ext_vector_type(8)));
typedef float  f32x4  __attribute__((ext_vector_type(4)));

__device__ __forceinline__ unsigned pk2bf(float a, float b) {   // RNE pack: 2 f32 -> bf16x2
    union { float f; unsigned u; } x, y; x.f = a; y.f = b;
    unsigned ru = x.u + 0x7fffu + ((x.u >> 16) & 1u);
    unsigned rv = y.u + 0x7fffu + ((y.u >> 16) & 1u);
    return (ru >> 16) | (rv & 0xffff0000u);
}

__device__ __forceinline__ unsigned short bf16r(float a) {      // RNE f32 -> bf16
    union { float f; unsigned u; } x; x.f = a;
    unsigned r = x.u + 0x7fffu + ((x.u >> 16) & 1u);
    return (unsigned short)(r >> 16);
}

__device__ __forceinline__ void glds16(const void* g, void* l) {
    __builtin_amdgcn_global_load_lds(
        (const __attribute__((address_space(1))) void*)g,
        (__attribute__((address_space(3))) void*)l, 16, 0, 0);
}

// ---------------- K0: prep = {WiT transpose tiles: blocks 0..31} ∪
//                          {vQp partial GEMV: blocks 32..287} ----------------
__global__ __launch_bounds__(256) void prep_kernel(
        const float* __restrict__ Wi, const float* __restrict__ Wq,
        const float* __restrict__ vQ, const float* __restrict__ bq,
        unsigned short* __restrict__ WiT, float* __restrict__ vQpP)
{
    const int tid = threadIdx.x;
    if (blockIdx.x < 32) {
        // 64x64 tile transpose Wi[d][k] -> WiT[k][d] (bf16), coalesced both sides
        const int t = blockIdx.x;
        const int d0 = (t >> 2) * 64, k0 = (t & 3) * 64;
        __shared__ float sT[64][68];                 // pad 68: 16B-aligned rows
        const int r = tid >> 4, c4 = (tid & 15) * 4;
        #pragma unroll
        for (int i = 0; i < 4; ++i) {
            float4 v = *reinterpret_cast<const float4*>(
                Wi + (size_t)(d0 + r + i * 16) * CK + k0 + c4);
            *reinterpret_cast<float4*>(&sT[r + i * 16][c4]) = v;
        }
        __syncthreads();
        const int k = tid >> 2, dg = (tid & 3) * 16;
        unsigned short __attribute__((aligned(16))) ov[16];
        #pragma unroll
        for (int j = 0; j < 16; ++j) ov[j] = bf16r(sT[dg + j][k]);
        unsigned short* dst = WiT + (size_t)(k0 + k) * CD + d0 + dg;
        *reinterpret_cast<uint4*>(dst)     = *reinterpret_cast<const uint4*>(&ov[0]);
        *reinterpret_cast<uint4*>(dst + 8) = *reinterpret_cast<const uint4*>(&ov[8]);
    } else {
        // vQpP[b][j][k] = sum_{d in 64-slice j} vQ[b][d]*Wq[d][k]  (+bq at j==0)
        const int bb = blockIdx.x - 32;
        const int b = bb >> 3, j = bb & 7;
        __shared__ float sq[64];
        if (tid < 64) sq[tid] = vQ[b * CD + j * 64 + tid];
        __syncthreads();
        float acc = (j == 0) ? bq[tid] : 0.f;
        const float* wq = Wq + (size_t)j * 64 * CK + tid;
        #pragma unroll
        for (int d = 0; d < 64; d += 8) {
            float wv[8];
            #pragma unroll
            for (int u = 0; u < 8; ++u) wv[u] = wq[(d + u) * CK];   // 8 loads in flight
            #pragma unroll
            for (int u = 0; u < 8; ++u) acc += sq[d + u] * wv[u];
        }
        vQpP[(size_t)bb * CK + tid] = acc;
    }
}

// ---------------- K1: fused scores + online-softmax + K-space num ----------------
// BM=128 rows/block, BK=64, 8 K-steps. grid (16, 32).
// NEW wave mapping: wave w owns A-rows [32w,32w+32) x ALL 256 K-cols.
//  -> A private per wave: each vI byte loaded ONCE per block, direct global->reg,
//     pipelined one full K-step ahead (ping-pong reg sets).
//  -> B shared via swizzled glds double-buffer (prefetch before compute),
//     consumed as 32 conflict-free ds_read_b128 per wave per step.
// One barrier per K-step.
__global__ __launch_bounds__(256, 2) void scores_fused_kernel(
        const float* __restrict__ vI, const unsigned short* __restrict__ WiT,
        const float* __restrict__ vQpP, const float* __restrict__ Wp,
        float* __restrict__ numP, float* __restrict__ Zp, float* __restrict__ mP)
{
    constexpr int BM = 128, BK = 64;
    __shared__ __align__(16) unsigned short sB[2][CK * BK];   // 2 x 32 KB
    float* fb   = (float*)sB[0];      // aliased AFTER the K-loop only
    float* svq  = fb;                 // [256] combined vQp
    float* swp  = fb + 256;           // [256] Wp
    float* sS   = fb + 512;           // [128] row scores
    float* sW   = fb + 640;           // [128] exp weights
    float* snum = fb + 768;           // [4][256] num wave-partials

    const int tid  = threadIdx.x;
    const int b    = blockIdx.y;
    const int n0   = blockIdx.x * BM;
    const int wave = tid >> 6;
    const int lane = tid & 63;
    const int col  = lane & 15;
    const int quad = lane >> 4;

    const float* vIb   = vI + ((size_t)b * CN + n0) * CD;
    // A-row for (mt): 32*wave + mt*16 + col ; k-chunk quad*8 (+s*32)
    const float* aBase = vIb + (size_t)(wave * 32 + col) * CD + quad * 8;

    // B glds source offsets (swizzled chunk): instr i covers rows wave*64+i*8 .. +8
    int gBoff[8];
    #pragma unroll
    for (int i = 0; i < 8; ++i) {
        int row = wave * 64 + i * 8 + (lane >> 3);
        int c   = (lane & 7) ^ (row & 7);
        gBoff[i] = row * CD + c * 8;    // ushort index; +d0 per chunk
    }

    f32x4 acc[2][16];
    #pragma unroll
    for (int mt = 0; mt < 2; ++mt)
        #pragma unroll
        for (int kt = 0; kt < 16; ++kt)
            acc[mt][kt] = (f32x4){0.f, 0.f, 0.f, 0.f};

    f32x4 aA[8], aB2[8];   // ping-pong A regs: idx = mt*4 + s*2 + half

    auto loadA = [&](f32x4* dst, int d0) {
        #pragma unroll
        for (int mt = 0; mt < 2; ++mt)
            #pragma unroll
            for (int s = 0; s < 2; ++s) {
                const float* p = aBase + (size_t)(mt * 16) * CD + d0 + s * 32;
                dst[mt * 4 + s * 2]     = *reinterpret_cast<const f32x4*>(p);
                dst[mt * 4 + s * 2 + 1] = *reinterpret_cast<const f32x4*>(p + 4);
            }
    };
    auto stageB = [&](int d0, int buf) {
        #pragma unroll
        for (int i = 0; i < 8; ++i)
            glds16(WiT + gBoff[i] + d0,
                   (unsigned short*)sB[buf] + (wave * 8 + i) * 512);
    };
    auto compute = [&](const f32x4* ar, const unsigned short* bufC) {
        bf16x8 af[2][2];
        #pragma unroll
        for (int mt = 0; mt < 2; ++mt)
            #pragma unroll
            for (int s = 0; s < 2; ++s) {
                union { unsigned u[4]; bf16x8 v; } t;
                const f32x4 lo = ar[mt * 4 + s * 2], hi = ar[mt * 4 + s * 2 + 1];
                t.u[0] = pk2bf(lo.x, lo.y); t.u[1] = pk2bf(lo.z, lo.w);
                t.u[2] = pk2bf(hi.x, hi.y); t.u[3] = pk2bf(hi.z, hi.w);
                af[mt][s] = t.v;
            }
        #pragma unroll
        for (int s = 0; s < 2; ++s) {
            const int slot = (4 * s + quad) ^ (col & 7);
            #pragma unroll
            for (int kc = 0; kc < 4; ++kc) {
                bf16x8 bfr[4];
                #pragma unroll
                for (int u = 0; u < 4; ++u) {
                    int R = (kc * 4 + u) * 16 + col;
                    bfr[u] = *reinterpret_cast<const bf16x8*>(bufC + R * 64 + slot * 8);
                }
                #pragma unroll
                for (int u = 0; u < 4; ++u)
                    #pragma unroll
                    for (int mt = 0; mt < 2; ++mt)
                        acc[mt][kc * 4 + u] = __builtin_amdgcn_mfma_f32_16x16x32_bf16(
                            af[mt][s], bfr[u], acc[mt][kc * 4 + u], 0, 0, 0);
            }
        }
    };

    // prologue: A(0) and B(0) in flight together
    loadA(aA, 0);
    stageB(0, 0);
    __syncthreads();

    for (int tt = 0; tt < 4; ++tt) {
        const int d0 = tt * 128;
        // even step t=2tt: prefetch A/B for t+1, compute vs sB[0]
        loadA(aB2, d0 + 64);
        stageB(d0 + 64, 1);
        compute(aA, sB[0]);
        __syncthreads();
        // odd step t=2tt+1: prefetch A/B for t+1 (if any), compute vs sB[1]
        if (tt < 3) {
            loadA(aA, d0 + 128);
            stageB(d0 + 128, 0);
        }
        compute(aB2, sB[1]);
        __syncthreads();
    }

    // ---- epilogue 0: combine vQp partials + Wp into LDS (alias on sB[0]) ----
    {
        float a = 0.f;
        #pragma unroll
        for (int j = 0; j < 8; ++j) a += vQpP[(b * 8 + j) * CK + tid];
        svq[tid] = a;
        swp[tid] = Wp[tid];
    }
    __syncthreads();

    // ---- epilogue 1: per-row scores ----
    float vq[16], wp[16];
    #pragma unroll
    for (int kt = 0; kt < 16; ++kt) {
        vq[kt] = svq[kt * 16 + col];
        wp[kt] = swp[kt * 16 + col];
    }
    float sp[2][4];
    #pragma unroll
    for (int mt = 0; mt < 2; ++mt)
        #pragma unroll
        for (int r = 0; r < 4; ++r) {
            float s = 0.f;
            #pragma unroll
            for (int kt = 0; kt < 16; ++kt) {
                float v = acc[mt][kt][r] + vq[kt];
                v = v > 0.f ? v : 0.01f * v;
                s += v * wp[kt];
            }
            sp[mt][r] = s;
        }
    #pragma unroll
    for (int off = 1; off < 16; off <<= 1)
        #pragma unroll
        for (int mt = 0; mt < 2; ++mt)
            #pragma unroll
            for (int r = 0; r < 4; ++r)
                sp[mt][r] += __shfl_xor(sp[mt][r], off);
    if (col == 0) {
        #pragma unroll
        for (int mt = 0; mt < 2; ++mt)
            #pragma unroll
            for (int r = 0; r < 4; ++r)
                sS[wave * 32 + mt * 16 + quad * 4 + r] = sp[mt][r];
    }
    __syncthreads();

    // ---- epilogue 2: block-local softmax pieces ----
    float m = -1e30f;
    #pragma unroll 8
    for (int i = 0; i < BM; ++i) m = fmaxf(m, sS[i]);
    if (tid < BM) sW[tid] = __expf(sS[tid] - m);
    __syncthreads();
    float z = (tid < BM) ? sW[tid] : 0.f;
    #pragma unroll
    for (int off = 32; off > 0; off >>= 1) z += __shfl_xor(z, off);
    if (lane == 0) sS[wave] = z;     // scores no longer needed
    __syncthreads();
    const int pidx = b * 16 + blockIdx.x;
    if (tid == 0) {
        Zp[pidx] = sS[0] + sS[1] + sS[2] + sS[3];
        mP[pidx] = m;
    }

    // ---- epilogue 3: K-space num from acc registers (vI never re-read) ----
    float w8[2][4];
    #pragma unroll
    for (int mt = 0; mt < 2; ++mt)
        #pragma unroll
        for (int r = 0; r < 4; ++r)
            w8[mt][r] = sW[wave * 32 + mt * 16 + quad * 4 + r];
    float nk[16];
    #pragma unroll
    for (int kt = 0; kt < 16; ++kt) {
        float s = 0.f;
        #pragma unroll
        for (int mt = 0; mt < 2; ++mt)
            #pragma unroll
            for (int r = 0; r < 4; ++r)
                s += w8[mt][r] * acc[mt][kt][r];
        s += __shfl_xor(s, 16);      // reduce across quads (rows)
        s += __shfl_xor(s, 32);
        nk[kt] = s;
    }
    if (quad == 0) {
        #pragma unroll
        for (int kt = 0; kt < 16; ++kt)
            snum[wave * 256 + kt * 16 + col] = nk[kt];
    }
    __syncthreads();
    numP[(size_t)pidx * CK + tid] =
        snum[tid] + snum[256 + tid] + snum[512 + tid] + snum[768 + tid];
}

// ---------------- K2: combine partials -> out = num/Z + vQp (elementwise) ----------------
__global__ __launch_bounds__(256) void finalize_kernel(
        const float* __restrict__ numP, const float* __restrict__ Zp,
        const float* __restrict__ mP, const float* __restrict__ vQpP,
        float* __restrict__ out)
{
    const int b = blockIdx.x, tid = threadIdx.x;
    float M = -1e30f;
    #pragma unroll
    for (int j = 0; j < 16; ++j) M = fmaxf(M, mP[b * 16 + j]);
    float w[16]; float Zt = 0.f;
    #pragma unroll
    for (int j = 0; j < 16; ++j) {
        w[j] = __expf(mP[b * 16 + j] - M);
        Zt += w[j] * Zp[b * 16 + j];
    }
    const float inv = 1.f / Zt;
    float s = 0.f;
    #pragma unroll
    for (int j = 0; j < 16; ++j) s += w[j] * numP[(size_t)(b * 16 + j) * CK + tid];
    float vq = 0.f;
    #pragma unroll
    for (int j = 0; j < 8; ++j) vq += vQpP[(size_t)(b * 8 + j) * CK + tid];
    out[b * CK + tid] = s * inv + vq;
}

extern "C" void kernel_launch(void* const* d_in, const int* in_sizes, int n_in,
                              void* d_out, int out_size, void* d_ws, size_t ws_size,
                              hipStream_t stream)
{
    const float* vI = (const float*)d_in[0];   // [B,N,D]
    const float* vQ = (const float*)d_in[1];   // [B,D]
    const float* Wi = (const float*)d_in[2];   // [D,K]
    const float* Wq = (const float*)d_in[3];   // [D,K]
    const float* bq = (const float*)d_in[4];   // [K]
    const float* Wp = (const float*)d_in[5];   // [K,1]
    // d_in[6] = bp: softmax-invariant, unused
    float* out = (float*)d_out;                // [B,K]

    char* ws = (char*)d_ws;
    float*          vQpP = (float*)(ws);                   // 256 KB  [32*8][256]
    unsigned short* WiT  = (unsigned short*)(ws + 262144); // 256 KB  [256][512]
    float*          numP = (float*)(ws + 524288);          // 512 KB  [32*16][256]
    float*          Zp   = (float*)(ws + 524288 + 524288); //   2 KB
    float*          mP   = (float*)(ws + 1048576 + 2048);  //   2 KB

    prep_kernel        <<<288, 256, 0, stream>>>(Wi, Wq, vQ, bq, WiT, vQpP);
    scores_fused_kernel<<<dim3(CN / 128, CB), 256, 0, stream>>>(vI, WiT, vQpP, Wp,
                                                                numP, Zp, mP);
    finalize_kernel    <<<CB, 256, 0, stream>>>(numP, Zp, mP, vQpP, out);
}